// Round 3
// baseline (884.351 us; speedup 1.0000x reference)
//
#include <hip/hip_runtime.h>
#include <hip/hip_cooperative_groups.h>

namespace cg = cooperative_groups;

// KGE graph encoder, pruned to the backward cone of the 64 CLS nodes.
// R2: block-aggregated frontier scans; 8-node-tiled feat0.
// R3: fused per-node layer kernels. R4: in-scan edge bucketing, 8 launches.
// R5: ONE cooperative kernel, 6 grid.sync()s. Slot IDs assigned in-batch at
// scan flush (kills finS1/finS0); S1 = prefix of S0, shared allocator+list;
// CLS hit-test via LDS binary search over goffs (kills slot2+its init);
// rel-projection overlapped with seed phase. ~10us/launch x7 gaps removed.

#define NN   50000      // N_NODES
#define NE   800000     // N_EDGES
#define NR   500        // N_REL
#define HH   8          // heads
#define DD   16         // per-head dim
#define HIDD 128        // HID == IN
#define BB   64         // batch (CLS nodes)

#define MAXS1 16448     // cap on |S1|           (expect ~1.1K)
#define MAXS0 50000     // cap on |S0|, <= NN    (expect ~16K)
#define MAXD1 256       // per-node layer-1 bucket cap (in-deg ~Poisson(16))
#define MAXD2 256       // per-graph layer-2 bucket cap
#define NBUF  512       // LDS node-append buffer
#define FT    8         // feat0 nodes per tile
#define GRID  1024      // 4 blocks/CU x 256 CUs (co-resident, cooperative)
#define TPB   256

#define VREAD(x) (*((volatile int*)&(x)))

// counters: [0] = S1/S0 joint allocator (seeded to BB), [1] = S0 extra count

__global__ __launch_bounds__(TPB, 4)
void k_fused(const float* __restrict__ ent_table, const float* __restrict__ rel_table,
             const float* __restrict__ W_ent, const float* __restrict__ W_rel,
             const float* __restrict__ attn_l, const float* __restrict__ attn_r,
             const float* __restrict__ attn_e,
             const int* __restrict__ ent_ids, const int* __restrict__ rel_ids,
             const int* __restrict__ src, const int* __restrict__ dst,
             const int* __restrict__ goffs,
             float* __restrict__ out,
             float* __restrict__ rproj, float* __restrict__ ee,
             int* __restrict__ slot1, int* __restrict__ slot0,
             int* __restrict__ nodes, int* __restrict__ counters,
             int* __restrict__ c1, int* __restrict__ c2,
             int* __restrict__ ebuck1, int* __restrict__ ebuck2,
             float* __restrict__ feat0, float* __restrict__ el0, float* __restrict__ er0,
             float* __restrict__ feat1, float* __restrict__ el1, float* __restrict__ er1)
{
    cg::grid_group grid = cg::this_grid();
    const int t = threadIdx.x, b = blockIdx.x;
    const int gsz = gridDim.x;
    const int gtid = b * TPB + t, gstr = gsz * TPB;

    __shared__ int   lN[NBUF];
    __shared__ int   cNsh, baseN;
    __shared__ int   goffsSh[BB];
    __shared__ float sh[FT][HIDD];            // feat0 tiles / rel rows
    __shared__ int   eks[2][MAXD1];           // layer phases, 2 nodes/block
    __shared__ int   erid[2][MAXD1];
    __shared__ float exsh[2][MAXD1 * HH];     // 16 KB
    __shared__ float rowf[2][HIDD];
    __shared__ float ff[2][HIDD];

    const float* W_ent1  = W_ent  + HIDD * HIDD;
    const float* attn_l1 = attn_l + HH * DD;
    const float* attn_r1 = attn_r + HH * DD;
    const float* rproj0  = rproj;
    const float* rproj1  = rproj + (size_t)NR * HIDD;
    const float* ee0     = ee;
    const float* ee1     = ee + (size_t)NR * HH;

    // ---------------- P0: init ----------------
    for (int n = gtid; n < NN; n += gstr) { slot1[n] = -1; slot0[n] = -1; }
    for (int n = gtid; n < MAXS1; n += gstr) c1[n] = 0;
    if (gtid < BB) c2[gtid] = 0;
    if (gtid < 8) counters[gtid] = 0;
    grid.sync();

    // ---------------- P1: seed (block 0) + rel projection (2 pairs/block) ----
    if (b == 0) {
        if (t < BB) { int n = goffs[t]; slot1[n] = t; slot0[n] = t; nodes[t] = n; }
        if (t == 0) counters[0] = BB;
    }
    if (b < NR) {                       // blocks 0..499 cover 1000 (l,r) pairs
        int half = t >> 7, tc = t & 127;
        int p = b * 2 + half;           // p = l*NR + r
        int l = p / NR;
        sh[half][tc] = rel_table[(p % NR) * HIDD + tc];
        __syncthreads();
        const float* W = W_rel + (size_t)l * HIDD * HIDD;
        float acc = 0.f;
        for (int j = 0; j < HIDD; j++) acc += sh[half][j] * W[j * HIDD + tc];
        rproj[(size_t)p * HIDD + tc] = acc;
        sh[2 + half][tc] = acc;
        __syncthreads();
        if (tc < HH) {
            float s = 0.f;
            #pragma unroll
            for (int d = 0; d < DD; d++)
                s += sh[2 + half][tc * DD + d] * attn_e[(l * HH + tc) * DD + d];
            ee[p * HH + tc] = s;
        }
    }
    grid.sync();

    // ---------------- P2: scan2 (edges into CLS; discovers S1) --------------
    if (t < BB) goffsSh[t] = goffs[t];
    if (t == 0) cNsh = 0;
    __syncthreads();
    {
        int per = (NE + gsz - 1) / gsz;
        int lo = b * per, hi = lo + per; if (hi > NE) hi = NE;
        for (int base = lo; base < hi; base += TPB) {
            int e = base + t;
            if (e < hi) {
                int d = dst[e];
                int loI = 0;                       // 6-step search, sorted goffs
                if (goffsSh[32] <= d) loI = 32;
                if (goffsSh[loI + 16] <= d) loI += 16;
                if (goffsSh[loI + 8]  <= d) loI += 8;
                if (goffsSh[loI + 4]  <= d) loI += 4;
                if (goffsSh[loI + 2]  <= d) loI += 2;
                if (goffsSh[loI + 1]  <= d) loI += 1;
                if (goffsSh[loI] == d) {
                    int g = loI;
                    int pos = atomicAdd(&c2[g], 1);
                    if (pos < MAXD2) ebuck2[g * MAXD2 + pos] = e;
                    int s = src[e];
                    if (atomicCAS(&slot1[s], -1, -2) == -1) {
                        int p2 = atomicAdd(&cNsh, 1);
                        lN[p2] = s;
                    }
                }
            }
            __syncthreads();
            if (cNsh >= NBUF - TPB) {
                int nN = cNsh;
                if (t == 0) baseN = atomicAdd(&counters[0], nN);
                __syncthreads();
                for (int i = t; i < nN; i += TPB) {
                    int pos = baseN + i;
                    if (pos < MAXS1) { int s = lN[i]; slot1[s] = pos; slot0[s] = pos; nodes[pos] = s; }
                }
                __syncthreads();
                if (t == 0) cNsh = 0;
            }
            __syncthreads();
        }
        int nN = cNsh;
        if (t == 0) baseN = atomicAdd(&counters[0], nN);
        __syncthreads();
        for (int i = t; i < nN; i += TPB) {
            int pos = baseN + i;
            if (pos < MAXS1) { int s = lN[i]; slot1[s] = pos; slot0[s] = pos; nodes[pos] = s; }
        }
    }
    grid.sync();

    // ---------------- P3: scan1 (edges into S1; discovers S0) ---------------
    int s1cnt = VREAD(counters[0]); if (s1cnt > MAXS1) s1cnt = MAXS1;
    if (t == 0) cNsh = 0;
    __syncthreads();
    {
        int per = (NE + gsz - 1) / gsz;
        int lo = b * per, hi = lo + per; if (hi > NE) hi = NE;
        for (int base = lo; base < hi; base += TPB) {
            int e = base + t;
            if (e < hi) {
                int d = dst[e];
                int kd = slot1[d];
                if (kd >= 0) {
                    int pos = atomicAdd(&c1[kd], 1);
                    if (pos < MAXD1) ebuck1[kd * MAXD1 + pos] = e;
                    int s = src[e];
                    if (atomicCAS(&slot0[s], -1, -2) == -1) {
                        int p2 = atomicAdd(&cNsh, 1);
                        lN[p2] = s;
                    }
                }
            }
            __syncthreads();
            if (cNsh >= NBUF - TPB) {
                int nN = cNsh;
                if (t == 0) baseN = s1cnt + atomicAdd(&counters[1], nN);
                __syncthreads();
                for (int i = t; i < nN; i += TPB) {
                    int pos = baseN + i;
                    if (pos < MAXS0) { int s = lN[i]; slot0[s] = pos; nodes[pos] = s; }
                }
                __syncthreads();
                if (t == 0) cNsh = 0;
            }
            __syncthreads();
        }
        int nN = cNsh;
        if (t == 0) baseN = s1cnt + atomicAdd(&counters[1], nN);
        __syncthreads();
        for (int i = t; i < nN; i += TPB) {
            int pos = baseN + i;
            if (pos < MAXS0) { int s = lN[i]; slot0[s] = pos; nodes[pos] = s; }
        }
    }
    grid.sync();

    // ---------------- P4: feat0 + el0/er0 for all S0 ------------------------
    int cnt0 = s1cnt + VREAD(counters[1]); if (cnt0 > MAXS0) cnt0 = MAXS0;
    {
        int half = t >> 7, tc = t & 127;
        int nT = (cnt0 + FT - 1) / FT;
        for (int tile = b; tile < nT; tile += gsz) {
            int k0 = tile * FT;
            for (int m = half; m < FT; m += 2) {
                int k = k0 + m;
                int n = nodes[k < cnt0 ? k : 0];
                sh[m][tc] = ent_table[(long)ent_ids[n] * HIDD + tc];
            }
            __syncthreads();
            float a0 = 0.f, a1 = 0.f, a2 = 0.f, a3 = 0.f;
            int mb = half * 4;
            for (int j = 0; j < HIDD; j++) {
                float w = W_ent[j * HIDD + tc];
                a0 += sh[mb + 0][j] * w; a1 += sh[mb + 1][j] * w;
                a2 += sh[mb + 2][j] * w; a3 += sh[mb + 3][j] * w;
            }
            __syncthreads();
            float av4[4] = {a0, a1, a2, a3};
            #pragma unroll
            for (int mi = 0; mi < 4; mi++) {
                int k = k0 + mb + mi;
                if (k < cnt0) feat0[(size_t)k * HIDD + tc] = av4[mi];
                sh[mb + mi][tc] = av4[mi];
            }
            __syncthreads();
            if (t < 128) {   // 8 nodes x 8 heads x {el,er} = 128 tasks
                int m = t >> 4, idx = t & 15, hh = idx >> 1, isR = idx & 1;
                int k = k0 + m;
                if (k < cnt0) {
                    const float* av = (isR ? attn_r : attn_l) + hh * DD;
                    float s = 0.f;
                    #pragma unroll
                    for (int d = 0; d < DD; d++) s += sh[m][hh * DD + d] * av[d];
                    if (isR) er0[k * HH + hh] = s; else el0[k * HH + hh] = s;
                }
            }
            __syncthreads();
        }
    }
    grid.sync();

    // ---------------- P5: fused layer-1 (2 nodes per block) -----------------
    {
        int half = t >> 7, tc = t & 127, h = tc >> 4;
        for (int kb = b * 2; kb < s1cnt; kb += gsz * 2) {
            int k = kb + half;
            bool act = k < s1cnt;
            int deg = 0;
            if (act) { deg = c1[k]; if (deg > MAXD1) deg = MAXD1; }
            for (int i = tc; i < deg; i += 128) {
                int e = ebuck1[k * MAXD1 + i];
                eks[half][i]  = slot0[src[e]];
                erid[half][i] = rel_ids[e];
            }
            __syncthreads();
            for (int idx = tc; idx < deg * HH; idx += 128) {
                int i = idx >> 3, hh = idx & 7;
                // er0 of dst: slot0(S1 node k) == k (S1 is the S0 prefix)
                float sc = el0[eks[half][i] * HH + hh] + er0[k * HH + hh]
                         + ee0[erid[half][i] * HH + hh];
                sc = sc >= 0.f ? sc : 0.2f * sc;
                exsh[half][idx] = expf(sc);
            }
            __syncthreads();
            float acc = 0.f, den = 0.f;
            for (int i = 0; i < deg; i++) {
                float ex = exsh[half][i * HH + h];
                acc += (feat0[(size_t)eks[half][i] * HIDD + tc]
                      + rproj0[(size_t)erid[half][i] * HIDD + tc]) * ex;
                den += ex;
            }
            rowf[half][tc] = den > 0.f ? acc / den : 0.f;
            __syncthreads();
            float a2 = 0.f;
            for (int j = 0; j < HIDD; j++) a2 += rowf[half][j] * W_ent1[j * HIDD + tc];
            if (act) feat1[(size_t)k * HIDD + tc] = a2;
            ff[half][tc] = a2;
            __syncthreads();
            if (act) {
                if (tc < HH) {
                    float s = 0.f;
                    #pragma unroll
                    for (int d = 0; d < DD; d++) s += ff[half][tc * DD + d] * attn_l1[tc * DD + d];
                    el1[k * HH + tc] = s;
                } else if (tc < 2 * HH) {
                    int hh = tc - HH;
                    float s = 0.f;
                    #pragma unroll
                    for (int d = 0; d < DD; d++) s += ff[half][hh * DD + d] * attn_r1[hh * DD + d];
                    er1[k * HH + hh] = s;
                }
            }
            __syncthreads();
        }
    }
    grid.sync();

    // ---------------- P6: fused layer-2 + CLS output ------------------------
    if (b < BB / 2) {
        int half = t >> 7, tc = t & 127, h = tc >> 4;
        int g = b * 2 + half;
        int deg = c2[g]; if (deg > MAXD2) deg = MAXD2;
        for (int i = tc; i < deg; i += 128) {
            int e = ebuck2[g * MAXD2 + i];
            eks[half][i]  = slot1[src[e]];
            erid[half][i] = rel_ids[e];
        }
        __syncthreads();
        for (int idx = tc; idx < deg * HH; idx += 128) {
            int i = idx >> 3, hh = idx & 7;
            // er1 of dst: slot1(CLS of graph g) == g (seeded)
            float sc = el1[eks[half][i] * HH + hh] + er1[g * HH + hh]
                     + ee1[erid[half][i] * HH + hh];
            sc = sc >= 0.f ? sc : 0.2f * sc;
            exsh[half][idx] = expf(sc);
        }
        __syncthreads();
        float acc = 0.f, den = 0.f;
        for (int i = 0; i < deg; i++) {
            float ex = exsh[half][i * HH + h];
            acc += (feat1[(size_t)eks[half][i] * HIDD + tc]
                  + rproj1[(size_t)erid[half][i] * HIDD + tc]) * ex;
            den += ex;
        }
        out[g * HIDD + tc] = den > 0.f ? acc / den : 0.f;
    }
}

extern "C" void kernel_launch(void* const* d_in, const int* in_sizes, int n_in,
                              void* d_out, int out_size, void* d_ws, size_t ws_size,
                              hipStream_t stream) {
    const float* ent_table = (const float*)d_in[0];
    const float* rel_table = (const float*)d_in[1];
    const float* W_ent     = (const float*)d_in[2];   // [2,128,128]
    const float* W_rel     = (const float*)d_in[3];   // [2,128,128]
    const float* attn_l    = (const float*)d_in[4];   // [2,8,16]
    const float* attn_r    = (const float*)d_in[5];
    const float* attn_e    = (const float*)d_in[6];
    const int*   ent_ids   = (const int*)d_in[7];
    const int*   rel_ids   = (const int*)d_in[8];
    const int*   src       = (const int*)d_in[9];
    const int*   dst       = (const int*)d_in[10];
    const int*   goffs     = (const int*)d_in[11];
    float*       out       = (float*)d_out;

    char* p = (char*)d_ws;
    auto alloc = [&](size_t nbytes) {
        void* q = (void*)p;
        p += (nbytes + 255) & ~(size_t)255;
        return q;
    };
    float* rproj   = (float*)alloc((size_t)2 * NR * HIDD * 4);
    float* ee      = (float*)alloc((size_t)2 * NR * HH * 4);
    int*   slot1   = (int*)alloc((size_t)NN * 4);
    int*   slot0   = (int*)alloc((size_t)NN * 4);
    int*   nodes   = (int*)alloc((size_t)MAXS0 * 4);
    int*   counters= (int*)alloc(8 * 4);
    int*   c1      = (int*)alloc((size_t)MAXS1 * 4);
    int*   c2      = (int*)alloc((size_t)BB * 4);
    int*   ebuck1  = (int*)alloc((size_t)MAXS1 * MAXD1 * 4);
    int*   ebuck2  = (int*)alloc((size_t)BB * MAXD2 * 4);
    float* feat0   = (float*)alloc((size_t)MAXS0 * HIDD * 4);
    float* el0     = (float*)alloc((size_t)MAXS0 * HH * 4);
    float* er0     = (float*)alloc((size_t)MAXS0 * HH * 4);
    float* feat1   = (float*)alloc((size_t)MAXS1 * HIDD * 4);
    float* el1     = (float*)alloc((size_t)MAXS1 * HH * 4);
    float* er1     = (float*)alloc((size_t)MAXS1 * HH * 4);

    // Co-residency check once (host-only query; graph-capture safe).
    static int s_grid = 0;
    if (s_grid == 0) {
        int nb = 0;
        if (hipOccupancyMaxActiveBlocksPerMultiprocessor(&nb, k_fused, TPB, 0) != hipSuccess || nb <= 0)
            nb = 4;
        hipDeviceProp_t prop;
        int cu = 256;
        if (hipGetDeviceProperties(&prop, 0) == hipSuccess) cu = prop.multiProcessorCount;
        int cap = nb * cu;
        s_grid = cap < GRID ? cap : GRID;
        if (s_grid < 64) s_grid = 64;
    }

    void* args[] = {
        (void*)&ent_table, (void*)&rel_table, (void*)&W_ent, (void*)&W_rel,
        (void*)&attn_l, (void*)&attn_r, (void*)&attn_e,
        (void*)&ent_ids, (void*)&rel_ids, (void*)&src, (void*)&dst, (void*)&goffs,
        (void*)&out,
        (void*)&rproj, (void*)&ee,
        (void*)&slot1, (void*)&slot0, (void*)&nodes, (void*)&counters,
        (void*)&c1, (void*)&c2, (void*)&ebuck1, (void*)&ebuck2,
        (void*)&feat0, (void*)&el0, (void*)&er0,
        (void*)&feat1, (void*)&el1, (void*)&er1
    };
    hipLaunchCooperativeKernel((void*)k_fused, dim3(s_grid), dim3(TPB),
                               args, 0, stream);
}

// Round 5
// 399.416 us; speedup vs baseline: 2.2141x; 2.2141x over previous
//
#include <hip/hip_runtime.h>
#include <hip/hip_bf16.h>

// KGE graph encoder, pruned to the backward cone of the 64 CLS nodes.
// R2: block-aggregated frontier scans; 8-node-tiled feat0.
// R3: fused per-node layer kernels. R4: in-scan edge bucketing, 8 launches.
// R5 (REVERTED): one cooperative kernel -- cg::grid.sync() costs ~100us each
// on gfx950 (L2 flush x8 XCDs + spin storm); kernel boundaries are cheaper.
// R6: back to stream-ordered launches, 8 -> 6: slot IDs assigned in-batch at
// scan flush (kills k_seed/k_finS1 + slot2 array; CLS test = LDS binary
// search over goffs); rel-projection folded into k_init's idle blocks.
// R7: resubmit of R6 (infra failure last round) + defensive LDS bounds guard.

#define NN   50000      // N_NODES
#define NE   800000     // N_EDGES
#define NR   500        // N_REL
#define HH   8          // heads
#define DD   16         // per-head dim
#define HIDD 128        // HID == IN
#define BB   64         // batch (CLS nodes)

#define MAXS1 16448     // cap on |S1|           (expect ~1.1K)
#define MAXS0 50000     // cap on |S0|, <= NN    (expect ~16K)
#define MAXD1 256       // per-node layer-1 bucket cap (in-deg ~Poisson(16))
#define MAXD2 256       // per-graph layer-2 bucket cap
#define NBUF  512       // LDS node-append buffer
#define FT    8         // feat0 nodes per tile
#define TPB   256

// counters: [0] = S1/S0 joint allocator (seeded to BB), [1] = S0 extra count

// 6-step binary search over 64 sorted graph offsets in LDS; returns graph id
// if n is a CLS node else -1.
__device__ __forceinline__ int cls_lookup(const int* goffsSh, int n) {
    int lo = 0;
    if (goffsSh[32] <= n) lo = 32;
    if (goffsSh[lo + 16] <= n) lo += 16;
    if (goffsSh[lo + 8]  <= n) lo += 8;
    if (goffsSh[lo + 4]  <= n) lo += 4;
    if (goffsSh[lo + 2]  <= n) lo += 2;
    if (goffsSh[lo + 1]  <= n) lo += 1;
    return goffsSh[lo] == n ? lo : -1;
}

// Blocks [0,RELB): rproj[l][r][:] = rel_table[r] @ W_rel[l], ee head dots.
// Blocks [RELB,grid): init slot1/slot0 (seeding CLS nodes via binary search),
// zero c1/c2, init counters, seed nodes[g] = goffs[g].
#define RELB 500
__global__ void k_init(const int* __restrict__ goffs,
                       const float* __restrict__ rel_table,
                       const float* __restrict__ W_rel,
                       const float* __restrict__ attn_e,
                       float* __restrict__ rproj, float* __restrict__ ee,
                       int* __restrict__ slot1, int* __restrict__ slot0,
                       int* __restrict__ nodes,
                       int* __restrict__ c1, int* __restrict__ c2,
                       int* __restrict__ counters) {
    int b = blockIdx.x, t = threadIdx.x;
    if (b < RELB) {
        __shared__ float sh[4][HIDD];
        int half = t >> 7, tc = t & 127;
        int p = b * 2 + half;             // p = l*NR + r, p in [0,1000)
        int l = p / NR;
        sh[half][tc] = rel_table[(p % NR) * HIDD + tc];
        __syncthreads();
        const float* W = W_rel + (size_t)l * HIDD * HIDD;
        float acc = 0.f;
        for (int j = 0; j < HIDD; j++) acc += sh[half][j] * W[j * HIDD + tc];
        rproj[(size_t)p * HIDD + tc] = acc;
        sh[2 + half][tc] = acc;
        __syncthreads();
        if (tc < HH) {
            float s = 0.f;
            #pragma unroll
            for (int d = 0; d < DD; d++)
                s += sh[2 + half][tc * DD + d] * attn_e[(l * HH + tc) * DD + d];
            ee[p * HH + tc] = s;
        }
        return;
    }
    __shared__ int goffsSh[BB];
    if (t < BB) goffsSh[t] = goffs[t];
    __syncthreads();
    int nb = gridDim.x - RELB;
    int i = (b - RELB) * TPB + t, stride = nb * TPB;
    for (int n = i; n < NN; n += stride) {
        int g = cls_lookup(goffsSh, n);
        slot1[n] = g; slot0[n] = g;       // CLS node: slot == graph id; else -1
        if (g >= 0) nodes[g] = n;
    }
    for (int n = i; n < MAXS1; n += stride) c1[n] = 0;
    if (i < BB) c2[i] = 0;
    if (i < 8) counters[i] = (i == 0) ? BB : 0;
}

// scan2: edges whose dst is a CLS node (binary search) -> per-graph buckets;
// discovers S1 srcs, CAS-claims them, assigns slot1 AND slot0 (= joint S1/S0
// prefix id) at LDS-aggregated flush time.
__global__ void k_scan2(const int* __restrict__ src, const int* __restrict__ dst,
                        const int* __restrict__ goffs,
                        int* __restrict__ slot1, int* __restrict__ slot0,
                        int* __restrict__ nodes,
                        int* __restrict__ c2, int* __restrict__ ebuck2,
                        int* __restrict__ counters) {
    __shared__ int lN[NBUF];
    __shared__ int cNsh, baseN;
    __shared__ int goffsSh[BB];
    int t = threadIdx.x;
    if (t < BB) goffsSh[t] = goffs[t];
    if (t == 0) cNsh = 0;
    __syncthreads();
    int gsz = gridDim.x;
    int per = (NE + gsz - 1) / gsz;
    int lo = blockIdx.x * per, hi = lo + per; if (hi > NE) hi = NE;
    for (int base = lo; base < hi; base += TPB) {
        int e = base + t;
        if (e < hi) {
            int g = cls_lookup(goffsSh, dst[e]);
            if (g >= 0) {
                int pos = atomicAdd(&c2[g], 1);
                if (pos < MAXD2) ebuck2[g * MAXD2 + pos] = e;
                int s = src[e];
                if (atomicCAS(&slot1[s], -1, -2) == -1) {
                    int p2 = atomicAdd(&cNsh, 1);
                    if (p2 < NBUF) lN[p2] = s;
                }
            }
        }
        __syncthreads();
        if (cNsh >= NBUF - TPB) {
            int nN = cNsh; if (nN > NBUF) nN = NBUF;
            if (t == 0) baseN = atomicAdd(&counters[0], nN);
            __syncthreads();
            for (int i = t; i < nN; i += TPB) {
                int pos = baseN + i;
                if (pos < MAXS1) { int s = lN[i]; slot1[s] = pos; slot0[s] = pos; nodes[pos] = s; }
            }
            __syncthreads();
            if (t == 0) cNsh = 0;
        }
        __syncthreads();
    }
    int nN = cNsh; if (nN > NBUF) nN = NBUF;
    if (t == 0) baseN = atomicAdd(&counters[0], nN);
    __syncthreads();
    for (int i = t; i < nN; i += TPB) {
        int pos = baseN + i;
        if (pos < MAXS1) { int s = lN[i]; slot1[s] = pos; slot0[s] = pos; nodes[pos] = s; }
    }
}

// scan1: edges whose dst is in S1 -> per-node buckets; discovers S0 extras,
// assigns slot0 at flush (positions continue after the S1 prefix).
__global__ void k_scan1(const int* __restrict__ src, const int* __restrict__ dst,
                        const int* __restrict__ slot1, int* __restrict__ slot0,
                        int* __restrict__ nodes,
                        int* __restrict__ c1, int* __restrict__ ebuck1,
                        int* __restrict__ counters) {
    __shared__ int lN[NBUF];
    __shared__ int cNsh, baseN;
    int t = threadIdx.x;
    int s1cnt = counters[0]; if (s1cnt > MAXS1) s1cnt = MAXS1;
    if (t == 0) cNsh = 0;
    __syncthreads();
    int gsz = gridDim.x;
    int per = (NE + gsz - 1) / gsz;
    int lo = blockIdx.x * per, hi = lo + per; if (hi > NE) hi = NE;
    for (int base = lo; base < hi; base += TPB) {
        int e = base + t;
        if (e < hi) {
            int kd = slot1[dst[e]];
            if (kd >= 0) {
                int pos = atomicAdd(&c1[kd], 1);
                if (pos < MAXD1) ebuck1[kd * MAXD1 + pos] = e;
                int s = src[e];
                if (atomicCAS(&slot0[s], -1, -2) == -1) {
                    int p2 = atomicAdd(&cNsh, 1);
                    if (p2 < NBUF) lN[p2] = s;
                }
            }
        }
        __syncthreads();
        if (cNsh >= NBUF - TPB) {
            int nN = cNsh; if (nN > NBUF) nN = NBUF;
            if (t == 0) baseN = s1cnt + atomicAdd(&counters[1], nN);
            __syncthreads();
            for (int i = t; i < nN; i += TPB) {
                int pos = baseN + i;
                if (pos < MAXS0) { int s = lN[i]; slot0[s] = pos; nodes[pos] = s; }
            }
            __syncthreads();
            if (t == 0) cNsh = 0;
        }
        __syncthreads();
    }
    int nN = cNsh; if (nN > NBUF) nN = NBUF;
    if (t == 0) baseN = s1cnt + atomicAdd(&counters[1], nN);
    __syncthreads();
    for (int i = t; i < nN; i += TPB) {
        int pos = baseN + i;
        if (pos < MAXS0) { int s = lN[i]; slot0[s] = pos; nodes[pos] = s; }
    }
}

// feat0 + el0/er0 for all S0 nodes; 8 nodes per tile amortize W_ent passes.
__global__ void k_feat0(const int* __restrict__ nodes, const int* __restrict__ counters,
                        const int* __restrict__ ent_ids,
                        const float* __restrict__ ent_table, const float* __restrict__ W_ent,
                        const float* __restrict__ attn_l, const float* __restrict__ attn_r,
                        float* __restrict__ feat0, float* __restrict__ el0,
                        float* __restrict__ er0) {
    int t = threadIdx.x;              // 0..127
    int s1 = counters[0]; if (s1 > MAXS1) s1 = MAXS1;
    int cnt = s1 + counters[1]; if (cnt > MAXS0) cnt = MAXS0;
    __shared__ float sh[FT][HIDD];
    int nT = (cnt + FT - 1) / FT;
    for (int tile = blockIdx.x; tile < nT; tile += gridDim.x) {
        int k0 = tile * FT;
        #pragma unroll
        for (int m = 0; m < FT; m++) {
            int k = k0 + m;
            int n = nodes[k < cnt ? k : 0];
            sh[m][t] = ent_table[(long)ent_ids[n] * HIDD + t];
        }
        __syncthreads();
        float acc[FT];
        #pragma unroll
        for (int m = 0; m < FT; m++) acc[m] = 0.f;
        for (int j = 0; j < HIDD; j++) {
            float w = W_ent[j * HIDD + t];
            #pragma unroll
            for (int m = 0; m < FT; m++) acc[m] += sh[m][j] * w;  // LDS broadcast
        }
        __syncthreads();
        #pragma unroll
        for (int m = 0; m < FT; m++) {
            int k = k0 + m;
            if (k < cnt) feat0[(size_t)k * HIDD + t] = acc[m];
            sh[m][t] = acc[m];
        }
        __syncthreads();
        {   // 8 nodes x 8 heads x {el,er} = 128 tasks, one per thread
            int m = t >> 4, idx = t & 15, h = idx >> 1, isR = idx & 1;
            int k = k0 + m;
            if (k < cnt) {
                const float* av = (isR ? attn_r : attn_l) + h * DD;
                float s = 0.f;
                #pragma unroll
                for (int d = 0; d < DD; d++) s += sh[m][h * DD + d] * av[d];
                if (isR) er0[k * HH + h] = s; else el0[k * HH + h] = s;
            }
        }
        __syncthreads();
    }
}

// Fused layer-1, latency-parallel 3-phase (gather meta / scores / col accum),
// then normalize + W_ent[1] matvec + el1/er1. One S1 node per 128-thr block.
__global__ void k_layer1(const int* __restrict__ counters,
                         const int* __restrict__ c1, const int* __restrict__ ebuck1,
                         const int* __restrict__ src, const int* __restrict__ rel_ids,
                         const int* __restrict__ slot0,
                         const float* __restrict__ feat0, const float* __restrict__ rproj0,
                         const float* __restrict__ el0, const float* __restrict__ er0,
                         const float* __restrict__ ee0,
                         const float* __restrict__ W_ent1,
                         const float* __restrict__ attn_l1, const float* __restrict__ attn_r1,
                         float* __restrict__ feat1, float* __restrict__ el1,
                         float* __restrict__ er1) {
    int t = threadIdx.x;              // 0..127 (col)
    int h = t >> 4;                   // head of this col
    int cnt = counters[0]; if (cnt > MAXS1) cnt = MAXS1;
    __shared__ int   eks[MAXD1];
    __shared__ int   erid[MAXD1];
    __shared__ float exsh[MAXD1 * HH];   // 8 KB
    __shared__ float row[HIDD];
    __shared__ float f[HIDD];
    for (int k = blockIdx.x; k < cnt; k += gridDim.x) {
        int deg = c1[k]; if (deg > MAXD1) deg = MAXD1;
        for (int i = t; i < deg; i += 128) {
            int e = ebuck1[k * MAXD1 + i];
            eks[i]  = slot0[src[e]];
            erid[i] = rel_ids[e];
        }
        __syncthreads();
        for (int idx = t; idx < deg * HH; idx += 128) {
            int i = idx >> 3, hh = idx & 7;
            // er0 of dst: slot0(S1 node k) == k (S1 is the S0 prefix)
            float sc = el0[eks[i] * HH + hh] + er0[k * HH + hh] + ee0[erid[i] * HH + hh];
            sc = sc >= 0.f ? sc : 0.2f * sc;
            exsh[idx] = expf(sc);
        }
        __syncthreads();
        float acc = 0.f, den = 0.f;
        #pragma unroll 4
        for (int i = 0; i < deg; i++) {
            float ex = exsh[i * HH + h];
            acc += (feat0[(size_t)eks[i] * HIDD + t]
                  + rproj0[(size_t)erid[i] * HIDD + t]) * ex;
            den += ex;
        }
        row[t] = den > 0.f ? acc / den : 0.f;   // normalized h1 row
        __syncthreads();
        float a2 = 0.f;
        for (int j = 0; j < HIDD; j++) a2 += row[j] * W_ent1[j * HIDD + t];
        feat1[(size_t)k * HIDD + t] = a2;
        f[t] = a2;
        __syncthreads();
        if (t < HH) {
            float s = 0.f;
            #pragma unroll
            for (int d = 0; d < DD; d++) s += f[t * DD + d] * attn_l1[t * DD + d];
            el1[k * HH + t] = s;
        } else if (t < 2 * HH) {
            int hh = t - HH;
            float s = 0.f;
            #pragma unroll
            for (int d = 0; d < DD; d++) s += f[hh * DD + d] * attn_r1[hh * DD + d];
            er1[k * HH + hh] = s;
        }
        __syncthreads();
    }
}

// Fused layer-2 + CLS output: one block per graph, direct bucket iteration.
__global__ void k_layer2(const int* __restrict__ c2, const int* __restrict__ ebuck2,
                         const int* __restrict__ src, const int* __restrict__ rel_ids,
                         const int* __restrict__ slot1,
                         const float* __restrict__ feat1, const float* __restrict__ rproj1,
                         const float* __restrict__ el1, const float* __restrict__ er1,
                         const float* __restrict__ ee1,
                         float* __restrict__ out) {
    int g = blockIdx.x;               // 0..BB-1
    int t = threadIdx.x;              // 0..127
    int h = t >> 4;
    __shared__ int   eks[MAXD2];
    __shared__ int   erid[MAXD2];
    __shared__ float exsh[MAXD2 * HH];
    int deg = c2[g]; if (deg > MAXD2) deg = MAXD2;
    for (int i = t; i < deg; i += 128) {
        int e = ebuck2[g * MAXD2 + i];
        eks[i]  = slot1[src[e]];      // srcs of layer-2 edges are in S1
        erid[i] = rel_ids[e];
    }
    __syncthreads();
    for (int idx = t; idx < deg * HH; idx += 128) {
        int i = idx >> 3, hh = idx & 7;
        // er1 of dst: slot1(CLS of graph g) == g (init order)
        float sc = el1[eks[i] * HH + hh] + er1[g * HH + hh] + ee1[erid[i] * HH + hh];
        sc = sc >= 0.f ? sc : 0.2f * sc;
        exsh[idx] = expf(sc);
    }
    __syncthreads();
    float acc = 0.f, den = 0.f;
    #pragma unroll 4
    for (int i = 0; i < deg; i++) {
        float ex = exsh[i * HH + h];
        acc += (feat1[(size_t)eks[i] * HIDD + t]
              + rproj1[(size_t)erid[i] * HIDD + t]) * ex;
        den += ex;
    }
    out[g * HIDD + t] = den > 0.f ? acc / den : 0.f;
}

extern "C" void kernel_launch(void* const* d_in, const int* in_sizes, int n_in,
                              void* d_out, int out_size, void* d_ws, size_t ws_size,
                              hipStream_t stream) {
    const float* ent_table = (const float*)d_in[0];
    const float* rel_table = (const float*)d_in[1];
    const float* W_ent     = (const float*)d_in[2];   // [2,128,128]
    const float* W_rel     = (const float*)d_in[3];   // [2,128,128]
    const float* attn_l    = (const float*)d_in[4];   // [2,8,16]
    const float* attn_r    = (const float*)d_in[5];
    const float* attn_e    = (const float*)d_in[6];
    const int*   ent_ids   = (const int*)d_in[7];
    const int*   rel_ids   = (const int*)d_in[8];
    const int*   src       = (const int*)d_in[9];
    const int*   dst       = (const int*)d_in[10];
    const int*   goffs     = (const int*)d_in[11];
    float*       out       = (float*)d_out;

    char* p = (char*)d_ws;
    auto alloc = [&](size_t nbytes) {
        void* q = (void*)p;
        p += (nbytes + 255) & ~(size_t)255;
        return q;
    };
    float* rproj   = (float*)alloc((size_t)2 * NR * HIDD * 4);
    float* ee      = (float*)alloc((size_t)2 * NR * HH * 4);
    int*   slot1   = (int*)alloc((size_t)NN * 4);
    int*   slot0   = (int*)alloc((size_t)NN * 4);
    int*   nodes   = (int*)alloc((size_t)MAXS0 * 4);
    int*   counters= (int*)alloc(8 * 4);
    int*   c1      = (int*)alloc((size_t)MAXS1 * 4);
    int*   c2      = (int*)alloc((size_t)BB * 4);
    int*   ebuck1  = (int*)alloc((size_t)MAXS1 * MAXD1 * 4);
    int*   ebuck2  = (int*)alloc((size_t)BB * MAXD2 * 4);
    float* feat0   = (float*)alloc((size_t)MAXS0 * HIDD * 4);
    float* el0     = (float*)alloc((size_t)MAXS0 * HH * 4);
    float* er0     = (float*)alloc((size_t)MAXS0 * HH * 4);
    float* feat1   = (float*)alloc((size_t)MAXS1 * HIDD * 4);
    float* el1     = (float*)alloc((size_t)MAXS1 * HH * 4);
    float* er1     = (float*)alloc((size_t)MAXS1 * HH * 4);

    const float* rproj0 = rproj;
    const float* rproj1 = rproj + (size_t)NR * HIDD;
    const float* ee0 = ee;
    const float* ee1 = ee + (size_t)NR * HH;
    const float* W_ent0 = W_ent;
    const float* W_ent1 = W_ent + HIDD * HIDD;
    const float* attn_l1 = attn_l + HH * DD;
    const float* attn_r1 = attn_r + HH * DD;

    hipLaunchKernelGGL(k_init, dim3(RELB + 524), dim3(TPB), 0, stream,
                       goffs, rel_table, W_rel, attn_e, rproj, ee,
                       slot1, slot0, nodes, c1, c2, counters);
    hipLaunchKernelGGL(k_scan2, dim3(1024), dim3(TPB), 0, stream,
                       src, dst, goffs, slot1, slot0, nodes, c2, ebuck2, counters);
    hipLaunchKernelGGL(k_scan1, dim3(1024), dim3(TPB), 0, stream,
                       src, dst, slot1, slot0, nodes, c1, ebuck1, counters);
    hipLaunchKernelGGL(k_feat0, dim3(1024), dim3(HIDD), 0, stream,
                       nodes, counters, ent_ids, ent_table, W_ent0,
                       attn_l, attn_r, feat0, el0, er0);
    hipLaunchKernelGGL(k_layer1, dim3(1024), dim3(HIDD), 0, stream,
                       counters, c1, ebuck1, src, rel_ids, slot0,
                       feat0, rproj0, el0, er0, ee0, W_ent1, attn_l1, attn_r1,
                       feat1, el1, er1);
    hipLaunchKernelGGL(k_layer2, dim3(BB), dim3(HIDD), 0, stream,
                       c2, ebuck2, src, rel_ids, slot1,
                       feat1, rproj1, el1, er1, ee1, out);
}